// Round 4
// baseline (783.870 us; speedup 1.0000x reference)
//
#include <hip/hip_runtime.h>

typedef unsigned short ushort_t;
typedef __bf16 bf16x8 __attribute__((ext_vector_type(8)));
typedef float f32x4 __attribute__((ext_vector_type(4)));

#define N_NODES 100000
#define M_PAD   100096   // 782 * 128
#define D_IN    1024
#define D_OUT   512
#define B_SZ    8192
#define K_NB    64

__device__ __forceinline__ ushort_t f2bf(float f) {
    unsigned int u = __builtin_bit_cast(unsigned int, f);
    u += 0x7FFFu + ((u >> 16) & 1u);   // round-to-nearest-even
    return (ushort_t)(u >> 16);
}
__device__ __forceinline__ float bflo(unsigned d) {
    return __builtin_bit_cast(float, d << 16);
}
__device__ __forceinline__ float bfhi(unsigned d) {
    return __builtin_bit_cast(float, d & 0xFFFF0000u);
}

// async global -> LDS, 16 B per lane (global src per-lane, LDS dest linear)
__device__ __forceinline__ void gload16(const ushort_t* g, ushort_t* l) {
    __builtin_amdgcn_global_load_lds(
        (const __attribute__((address_space(1))) void*)g,
        (__attribute__((address_space(3))) void*)l,
        16, 0, 0);
}

// 8x f32 -> bf16x8 (compiler emits v_cvt_pk_bf16_f32 pairs, RNE)
__device__ __forceinline__ bf16x8 pack8(float4 a, float4 b) {
    bf16x8 r;
    r[0] = (__bf16)a.x; r[1] = (__bf16)a.y;
    r[2] = (__bf16)a.z; r[3] = (__bf16)a.w;
    r[4] = (__bf16)b.x; r[5] = (__bf16)b.y;
    r[6] = (__bf16)b.z; r[7] = (__bf16)b.w;
    return r;
}

// ---------------------------------------------------------------------------
// Kernel 1: W [D_IN, D_OUT] f32  ->  Wt [D_OUT, D_IN] bf16 (transposed cast)
// ---------------------------------------------------------------------------
__global__ __launch_bounds__(256) void cast_w_kernel(
        const float* __restrict__ W, ushort_t* __restrict__ Wt) {
    int o = blockIdx.x * 256 + threadIdx.x;
    int n = o >> 10;
    int k = o & 1023;
    Wt[o] = f2bf(W[k * D_OUT + n]);
}

// ---------------------------------------------------------------------------
// Kernel 2: Enc[M_PAD,512] bf16 = X[*,1024] @ Wt[512,1024]^T + bias
// R3 counters: 254us, MfmaUtil 17%, hbm 16%, all pipes idle -> latency-bound
// on the 2-barrier-per-kstep drain. Fix: DOUBLE-BUFFERED LDS, ONE barrier
// per K-step (T3 minimum-2-phase): issue next-tile loads (A->regs, B->LDS
// buf q) BEFORE computing current tile from buf p; pack+ds_write A late
// (T14); single __syncthreads covers the in-flight loads.
//   - A read directly from f32 X, cvt to bf16 in reg-staging (no cast_x)
//   - B: global_load_lds, linear LDS dest, PRE-SWIZZLED global src (rule 21)
//   - 1D grid, XCD-bijective; m = logical>>2, n = logical&3 (A streamed once)
// ---------------------------------------------------------------------------
__global__ __launch_bounds__(256) void encode_gemm_kernel(
        const float* __restrict__ X, const ushort_t* __restrict__ Wt,
        const float* __restrict__ bias, ushort_t* __restrict__ Enc) {
    // 3128 blocks = 8 XCDs * 391: bijective XCD-contiguous remap
    int bid = blockIdx.x;
    int logical = (bid & 7) * 391 + (bid >> 3);
    int m0 = (logical >> 2) * 128;
    int n0 = (logical & 3) * 128;

    int tid = threadIdx.x;
    int lane = tid & 63;
    int wave = tid >> 6;
    int wm = (wave >> 1) * 64;
    int wn = (wave & 1) * 64;
    int quad = lane >> 4;
    int l16  = lane & 15;

    // double-buffered tiles: 2 x 128x32 bf16 = 2 x 8 KB each
    __shared__ __align__(16) ushort_t As[2 * 4096];
    __shared__ __align__(16) ushort_t Bs[2 * 4096];

    f32x4 acc[4][4];
    f32x4 zero = {0.f, 0.f, 0.f, 0.f};
    #pragma unroll
    for (int i = 0; i < 4; i++)
        #pragma unroll
        for (int j = 0; j < 4; j++)
            acc[i][j] = zero;

    int srow = tid >> 2;                    // staging row 0..63 (and +64)
    int kch  = tid & 3;                     // logical 16B k-chunk
    int schk = kch ^ ((srow >> 2) & 3);     // swizzled chunk position

    // B: global source pre-swizzled, LDS linear (chunk index == tid, tid+256)
    const ushort_t* gb = Wt + (size_t)(n0 + srow) * D_IN + schk * 8;
    ushort_t* lb = Bs + tid * 8;            // buffer 0; buffer 1 at +4096
    const size_t rowskip = (size_t)64 * D_IN;

    // A: f32 source (logical chunk), swizzled LDS write position
    int ar0 = m0 + srow;
    int ar1 = m0 + srow + 64;
    if (ar0 > N_NODES - 1) ar0 = N_NODES - 1;
    if (ar1 > N_NODES - 1) ar1 = N_NODES - 1;
    const float* pa0 = X + (size_t)ar0 * D_IN + kch * 8;
    const float* pa1 = X + (size_t)ar1 * D_IN + kch * 8;
    ushort_t* aw = As + srow * 32 + schk * 8;   // buffer 0; buffer 1 at +4096

    int rsw  = (l16 >> 2) & 3;
    int rchk = quad ^ rsw;

    // ---- prologue: stage tile 0 into buffer 0 ----
    {
        float4 f00 = *(const float4*)(pa0);
        float4 f01 = *(const float4*)(pa0 + 4);
        float4 f10 = *(const float4*)(pa1);
        float4 f11 = *(const float4*)(pa1 + 4);
        gload16(gb,           lb);
        gload16(gb + rowskip, lb + 2048);
        *(bf16x8*)(aw)           = pack8(f00, f01);
        *(bf16x8*)(aw + 64 * 32) = pack8(f10, f11);
    }
    __syncthreads();

    for (int it = 0; it < 32; ++it) {
        int p  = (it & 1) * 4096;       // compute buffer offset (ushorts)
        int q  = 4096 - p;              // stage buffer offset
        int k1 = it * 32 + 32;

        // ---- issue next-tile loads FIRST (latency hides under compute) ----
        float4 g00, g01, g10, g11;
        bool has_next = (k1 < D_IN);
        if (has_next) {
            g00 = *(const float4*)(pa0 + k1);
            g01 = *(const float4*)(pa0 + k1 + 4);
            g10 = *(const float4*)(pa1 + k1);
            g11 = *(const float4*)(pa1 + k1 + 4);
            gload16(gb + k1,           lb + q);
            gload16(gb + rowskip + k1, lb + q + 2048);
        }

        // ---- compute current tile from buffer p ----
        bf16x8 a[4], b[4];
        #pragma unroll
        for (int i = 0; i < 4; i++) {
            a[i] = *(const bf16x8*)(As + p + (wm + i * 16 + l16) * 32 + rchk * 8);
            b[i] = *(const bf16x8*)(Bs + p + (wn + i * 16 + l16) * 32 + rchk * 8);
        }
        #pragma unroll
        for (int i = 0; i < 4; i++)
            #pragma unroll
            for (int j = 0; j < 4; j++)
                acc[i][j] = __builtin_amdgcn_mfma_f32_16x16x32_bf16(
                                a[i], b[j], acc[i][j], 0, 0, 0);

        // ---- stage A for next tile late (write-late, T14) ----
        if (has_next) {
            *(bf16x8*)(aw + q)           = pack8(g00, g01);
            *(bf16x8*)(aw + q + 64 * 32) = pack8(g10, g11);
        }
        __syncthreads();   // single barrier: drains gloads + A writes
    }

    float bv[4];
    #pragma unroll
    for (int j = 0; j < 4; j++) bv[j] = bias[n0 + wn + j * 16 + l16];

    #pragma unroll
    for (int i = 0; i < 4; i++) {
        #pragma unroll
        for (int r = 0; r < 4; r++) {
            int grow = m0 + wm + i * 16 + quad * 4 + r;
            if (grow < N_NODES) {
                #pragma unroll
                for (int j = 0; j < 4; j++) {
                    int gcol = n0 + wn + j * 16 + l16;
                    Enc[(size_t)grow * D_OUT + gcol] = f2bf(acc[i][j][r] + bv[j]);
                }
            }
        }
    }
}

// ---------------------------------------------------------------------------
// Kernel 3: out[b,:] = sum_k val[b,k] * Enc[idx[b,k],:]   (f32 out)
// 1 KB rows, bias folded into Enc. (~218us by subtraction; likely at the
// random-access L3 fabric ceiling -- untouched this round.)
// ---------------------------------------------------------------------------
__global__ __launch_bounds__(256) void gather_out_kernel(
        const ushort_t* __restrict__ Enc, const int* __restrict__ idx,
        const float* __restrict__ val, float* __restrict__ out) {
    int b = blockIdx.x;
    int t = threadIdx.x;

    __shared__ int   sidx[K_NB];
    __shared__ float sval[K_NB];
    __shared__ float part[8 * 3 * 64];   // [e][h-1][c], conflict-free
    if (t < K_NB) {
        sidx[t] = idx[b * K_NB + t];
        sval[t] = val[b * K_NB + t];
    }
    __syncthreads();

    int h = t >> 6;      // neighbor group: rows k = h + 4*j, j = 0..15
    int c = t & 63;      // 16B chunk within the 1KB row

    float acc[8] = {0.f, 0.f, 0.f, 0.f, 0.f, 0.f, 0.f, 0.f};

    uint4 x[8];
    #pragma unroll
    for (int u = 0; u < 8; u++)
        x[u] = ((const uint4*)(Enc + (size_t)sidx[h + 4 * u] * D_OUT))[c];

    #pragma unroll
    for (int j0 = 0; j0 < 16; j0 += 8) {
        uint4 cur[8];
        #pragma unroll
        for (int u = 0; u < 8; u++) cur[u] = x[u];
        if (j0 + 8 < 16) {
            #pragma unroll
            for (int u = 0; u < 8; u++)
                x[u] = ((const uint4*)(
                    Enc + (size_t)sidx[h + 4 * (j0 + 8 + u)] * D_OUT))[c];
        }
        #pragma unroll
        for (int u = 0; u < 8; u++) {
            float v = sval[h + 4 * (j0 + u)];
            acc[0] = fmaf(v, bflo(cur[u].x), acc[0]);
            acc[1] = fmaf(v, bfhi(cur[u].x), acc[1]);
            acc[2] = fmaf(v, bflo(cur[u].y), acc[2]);
            acc[3] = fmaf(v, bfhi(cur[u].y), acc[3]);
            acc[4] = fmaf(v, bflo(cur[u].z), acc[4]);
            acc[5] = fmaf(v, bfhi(cur[u].z), acc[5]);
            acc[6] = fmaf(v, bflo(cur[u].w), acc[6]);
            acc[7] = fmaf(v, bfhi(cur[u].w), acc[7]);
        }
    }

    if (h != 0) {
        #pragma unroll
        for (int e = 0; e < 8; e++)
            part[e * 192 + (h - 1) * 64 + c] = acc[e];
    }
    __syncthreads();
    if (h == 0) {
        float r[8];
        #pragma unroll
        for (int e = 0; e < 8; e++)
            r[e] = acc[e] + part[e * 192 + c] + part[e * 192 + 64 + c]
                          + part[e * 192 + 128 + c];
        float4 o0 = {r[0], r[1], r[2], r[3]};
        float4 o1 = {r[4], r[5], r[6], r[7]};
        float* dst = out + (size_t)b * D_OUT + c * 8;
        *(float4*)(dst)     = o0;
        *(float4*)(dst + 4) = o1;
    }
}

// ---------------------------------------------------------------------------
// Fallback kernels (tiny workspace): gather in X-domain (f32) + small GEMM.
// ---------------------------------------------------------------------------
__global__ __launch_bounds__(256) void gather_f32_kernel(
        const float* __restrict__ X, const int* __restrict__ idx,
        const float* __restrict__ val, ushort_t* __restrict__ Y,
        float* __restrict__ s) {
    int b = blockIdx.x;
    int t = threadIdx.x;

    __shared__ int   sidx[K_NB];
    __shared__ float sval[K_NB];
    if (t < K_NB) {
        sidx[t] = idx[b * K_NB + t];
        sval[t] = val[b * K_NB + t];
    }
    __syncthreads();

    float ax = 0.f, ay = 0.f, az = 0.f, aw = 0.f;
    #pragma unroll 8
    for (int k = 0; k < K_NB; k++) {
        const float4* row = (const float4*)(X + (size_t)sidx[k] * D_IN);
        float4 x = row[t];
        float  v = sval[k];
        ax = fmaf(v, x.x, ax);
        ay = fmaf(v, x.y, ay);
        az = fmaf(v, x.z, az);
        aw = fmaf(v, x.w, aw);
    }
    uint2 o;
    o.x = (unsigned)f2bf(ax) | ((unsigned)f2bf(ay) << 16);
    o.y = (unsigned)f2bf(az) | ((unsigned)f2bf(aw) << 16);
    *(uint2*)(Y + (size_t)b * D_IN + t * 4) = o;

    if (t == 0) {
        float sum = 0.f;
        #pragma unroll
        for (int k = 0; k < K_NB; k++) sum += sval[k];
        s[b] = sum;
    }
}

__global__ __launch_bounds__(256) void gemm_kernel(
        const ushort_t* __restrict__ Y, const ushort_t* __restrict__ Wt,
        const float* __restrict__ s, const float* __restrict__ bias,
        float* __restrict__ out) {
    const int Kdim = D_IN;
    int m0 = blockIdx.x * 128;
    int n0 = blockIdx.y * 128;
    int t = threadIdx.x;
    int lane = t & 63;
    int wave = t >> 6;
    int wm = (wave >> 1) * 64;
    int wn = (wave & 1) * 64;
    int quad = lane >> 4;
    int l16  = lane & 15;

    __shared__ __align__(16) ushort_t As[128 * 32];
    __shared__ __align__(16) ushort_t Bs[128 * 32];

    f32x4 acc[4][4];
    f32x4 zero = {0.f, 0.f, 0.f, 0.f};
    #pragma unroll
    for (int i = 0; i < 4; i++)
        #pragma unroll
        for (int j = 0; j < 4; j++)
            acc[i][j] = zero;

    int rsw = (l16 >> 2) & 3;

    for (int k0 = 0; k0 < Kdim; k0 += 32) {
        #pragma unroll
        for (int i = 0; i < 2; i++) {
            int c   = t + i * 256;
            int row = c >> 2;
            int chk = c & 3;
            int pos = chk ^ ((row >> 2) & 3);
            *(int4*)(As + row * 32 + pos * 8) =
                *(const int4*)(Y + (size_t)(m0 + row) * Kdim + k0 + chk * 8);
            *(int4*)(Bs + row * 32 + pos * 8) =
                *(const int4*)(Wt + (size_t)(n0 + row) * Kdim + k0 + chk * 8);
        }
        __syncthreads();

        bf16x8 a[4], b[4];
        int rchk = quad ^ rsw;
        #pragma unroll
        for (int i = 0; i < 4; i++) {
            a[i] = *(const bf16x8*)(As + (wm + i * 16 + l16) * 32 + rchk * 8);
            b[i] = *(const bf16x8*)(Bs + (wn + i * 16 + l16) * 32 + rchk * 8);
        }
        #pragma unroll
        for (int i = 0; i < 4; i++)
            #pragma unroll
            for (int j = 0; j < 4; j++)
                acc[i][j] = __builtin_amdgcn_mfma_f32_16x16x32_bf16(
                                a[i], b[j], acc[i][j], 0, 0, 0);
        __syncthreads();
    }

    #pragma unroll
    for (int i = 0; i < 4; i++) {
        #pragma unroll
        for (int r = 0; r < 4; r++) {
            int grow = m0 + wm + i * 16 + quad * 4 + r;
            float sv = s[grow];
            #pragma unroll
            for (int j = 0; j < 4; j++) {
                int gcol = n0 + wn + j * 16 + l16;
                out[(size_t)grow * D_OUT + gcol] = acc[i][j][r] + sv * bias[gcol];
            }
        }
    }
}

// ---------------------------------------------------------------------------
extern "C" void kernel_launch(void* const* d_in, const int* in_sizes, int n_in,
                              void* d_out, int out_size, void* d_ws, size_t ws_size,
                              hipStream_t stream) {
    const float* X    = (const float*)d_in[0];
    const int*   idx  = (const int*)d_in[1];
    const float* val  = (const float*)d_in[2];
    const float* W    = (const float*)d_in[3];
    const float* bias = (const float*)d_in[4];
    float* out = (float*)d_out;

    const size_t ENC_BYTES = (size_t)M_PAD * D_OUT * 2;   // padded bf16 Enc
    const size_t WT_BYTES  = (size_t)D_OUT * D_IN * 2;
    const size_t Y_BYTES   = (size_t)B_SZ * D_IN * 2;     // fallback only

    char* ws = (char*)d_ws;
    bool fast = ws_size >= ENC_BYTES + WT_BYTES;

    if (fast) {
        ushort_t* Enc = (ushort_t*)ws;
        ushort_t* Wt  = (ushort_t*)(ws + ENC_BYTES);

        hipLaunchKernelGGL(cast_w_kernel, dim3((D_OUT * D_IN) / 256), dim3(256),
                           0, stream, W, Wt);
        hipLaunchKernelGGL(encode_gemm_kernel, dim3((M_PAD / 128) * (D_OUT / 128)),
                           dim3(256), 0, stream, X, Wt, bias, Enc);
        hipLaunchKernelGGL(gather_out_kernel, dim3(B_SZ), dim3(256),
                           0, stream, Enc, idx, val, out);
    } else {
        ushort_t* Yb = (ushort_t*)ws;
        ushort_t* Wt = (ushort_t*)(ws + Y_BYTES);
        float*    sb = (float*)(ws + Y_BYTES + WT_BYTES);

        hipLaunchKernelGGL(cast_w_kernel, dim3((D_OUT * D_IN) / 256), dim3(256),
                           0, stream, W, Wt);
        hipLaunchKernelGGL(gather_f32_kernel, dim3(B_SZ), dim3(256),
                           0, stream, X, idx, val, Yb, sb);
        hipLaunchKernelGGL(gemm_kernel, dim3(B_SZ / 128, D_OUT / 128), dim3(256),
                           0, stream, Yb, Wt, sb, bias, out);
    }
}

// Round 5
// 725.171 us; speedup vs baseline: 1.0809x; 1.0809x over previous
//
#include <hip/hip_runtime.h>

typedef unsigned short ushort_t;
typedef __bf16 bf16x8 __attribute__((ext_vector_type(8)));
typedef float f32x4 __attribute__((ext_vector_type(4)));

#define N_NODES 100000
#define M_PAD   100096   // 782 * 128
#define D_IN    1024
#define D_OUT   512
#define B_SZ    8192
#define K_NB    64

__device__ __forceinline__ ushort_t f2bf(float f) {
    unsigned int u = __builtin_bit_cast(unsigned int, f);
    u += 0x7FFFu + ((u >> 16) & 1u);   // round-to-nearest-even
    return (ushort_t)(u >> 16);
}
__device__ __forceinline__ float bflo(unsigned d) {
    return __builtin_bit_cast(float, d << 16);
}
__device__ __forceinline__ float bfhi(unsigned d) {
    return __builtin_bit_cast(float, d & 0xFFFF0000u);
}

// async global -> LDS, 16 B per lane (global src per-lane, LDS dest linear)
__device__ __forceinline__ void gload16(const ushort_t* g, ushort_t* l) {
    __builtin_amdgcn_global_load_lds(
        (const __attribute__((address_space(1))) void*)g,
        (__attribute__((address_space(3))) void*)l,
        16, 0, 0);
}

// 8x f32 -> bf16x8 (compiler emits v_cvt_pk_bf16_f32 pairs, RNE)
__device__ __forceinline__ bf16x8 pack8(float4 a, float4 b) {
    bf16x8 r;
    r[0] = (__bf16)a.x; r[1] = (__bf16)a.y;
    r[2] = (__bf16)a.z; r[3] = (__bf16)a.w;
    r[4] = (__bf16)b.x; r[5] = (__bf16)b.y;
    r[6] = (__bf16)b.z; r[7] = (__bf16)b.w;
    return r;
}

// ---------------------------------------------------------------------------
// Kernel 1: W [D_IN, D_OUT] f32  ->  Wt [D_OUT, D_IN] bf16 (transposed cast)
// ---------------------------------------------------------------------------
__global__ __launch_bounds__(256) void cast_w_kernel(
        const float* __restrict__ W, ushort_t* __restrict__ Wt) {
    int o = blockIdx.x * 256 + threadIdx.x;
    int n = o >> 10;
    int k = o & 1023;
    Wt[o] = f2bf(W[k * D_OUT + n]);
}

// ---------------------------------------------------------------------------
// Kernel 2: Enc[M_PAD,512] bf16 = X[*,1024] @ Wt[512,1024]^T + bias
// R4 post-mortem: explicit LDS dbuf REGRESSED (compiler vmcnt-drains before
// MFMA; m99/m100). R3 single-buffer was in-flight-bytes-bound (~96 B/lane ->
// ~1.3 TB/s by Little's law). This version: R3 structure with BK=64:
//   - 2x in-flight per thread (8 A dwordx4 + 4 B gload_lds = 192 B/lane)
//   - half the barriers (16 K-steps), each drain amortized over 2x MFMA
//   - LDS 32 KB single-buffer; XOR-8 swizzle (pos = kc ^ (row&7)), applied
//     write-side for A (reg->ds_write), source-side for B (rule 21), and
//     read-side for fragments
// ---------------------------------------------------------------------------
__global__ __launch_bounds__(256) void encode_gemm_kernel(
        const float* __restrict__ X, const ushort_t* __restrict__ Wt,
        const float* __restrict__ bias, ushort_t* __restrict__ Enc) {
    // 3128 blocks = 8 XCDs * 391: bijective XCD-contiguous remap
    int bid = blockIdx.x;
    int logical = (bid & 7) * 391 + (bid >> 3);
    int m0 = (logical >> 2) * 128;
    int n0 = (logical & 3) * 128;

    int tid = threadIdx.x;
    int lane = tid & 63;
    int wave = tid >> 6;
    int wm = (wave >> 1) * 64;
    int wn = (wave & 1) * 64;
    int quad = lane >> 4;
    int l16  = lane & 15;

    __shared__ __align__(16) ushort_t As[128 * 64];   // 16 KB
    __shared__ __align__(16) ushort_t Bs[128 * 64];   // 16 KB

    f32x4 acc[4][4];
    f32x4 zero = {0.f, 0.f, 0.f, 0.f};
    #pragma unroll
    for (int i = 0; i < 4; i++)
        #pragma unroll
        for (int j = 0; j < 4; j++)
            acc[i][j] = zero;

    // staging: chunk c = tid + i*256 (i=0..3); row = c>>3 = rb+32i, kc = c&7
    int rb  = tid >> 3;                 // row base 0..31
    int kc  = tid & 7;                  // logical 16B k-chunk 0..7
    int skc = kc ^ (rb & 7);            // swizzled position ((rb+32i)&7 == rb&7)

    // B: pre-swizzled global source, linear LDS dest (chunk order)
    const ushort_t* gb = Wt + (size_t)(n0 + rb) * D_IN + skc * 8;
    ushort_t* lb = Bs + tid * 8;        // + i*2048 ushorts per i

    // A: f32 source at logical chunk, ds_write at swizzled position
    const float* pa[4];
    #pragma unroll
    for (int i = 0; i < 4; i++) {
        int r = m0 + rb + 32 * i;
        if (r > N_NODES - 1) r = N_NODES - 1;
        pa[i] = X + (size_t)r * D_IN + kc * 8;
    }
    ushort_t* aw = As + rb * 64 + skc * 8;   // + i*2048 ushorts per i

    int rsw = l16 & 7;                  // read swizzle (row&7 == l16&7)

    // prologue: A regs for k0 = 0
    float4 f[4][2];
    #pragma unroll
    for (int i = 0; i < 4; i++) {
        f[i][0] = *(const float4*)(pa[i]);
        f[i][1] = *(const float4*)(pa[i] + 4);
    }

    for (int k0 = 0; k0 < D_IN; k0 += 64) {
        // stage current A (regs -> LDS, swizzled), issue current B gloads
        #pragma unroll
        for (int i = 0; i < 4; i++)
            *(bf16x8*)(aw + i * 2048) = pack8(f[i][0], f[i][1]);
        #pragma unroll
        for (int i = 0; i < 4; i++)
            gload16(gb + k0 + (size_t)i * 32 * D_IN, lb + i * 2048);
        __syncthreads();   // drains vmcnt+lgkm: tile ready

        // prefetch next-step A early (hides HBM latency under MFMA phase)
        if (k0 + 64 < D_IN) {
            #pragma unroll
            for (int i = 0; i < 4; i++) {
                f[i][0] = *(const float4*)(pa[i] + k0 + 64);
                f[i][1] = *(const float4*)(pa[i] + k0 + 68);
            }
        }

        // compute: two k-substeps of 32
        #pragma unroll
        for (int s = 0; s < 2; s++) {
            bf16x8 a[4], b[4];
            int pos = ((s * 4 + quad) ^ rsw) * 8;
            #pragma unroll
            for (int i = 0; i < 4; i++) {
                a[i] = *(const bf16x8*)(As + (wm + i * 16 + l16) * 64 + pos);
                b[i] = *(const bf16x8*)(Bs + (wn + i * 16 + l16) * 64 + pos);
            }
            #pragma unroll
            for (int i = 0; i < 4; i++)
                #pragma unroll
                for (int j = 0; j < 4; j++)
                    acc[i][j] = __builtin_amdgcn_mfma_f32_16x16x32_bf16(
                                    a[i], b[j], acc[i][j], 0, 0, 0);
        }
        __syncthreads();   // all waves done reading before next staging
    }

    float bv[4];
    #pragma unroll
    for (int j = 0; j < 4; j++) bv[j] = bias[n0 + wn + j * 16 + l16];

    #pragma unroll
    for (int i = 0; i < 4; i++) {
        #pragma unroll
        for (int r = 0; r < 4; r++) {
            int grow = m0 + wm + i * 16 + quad * 4 + r;
            if (grow < N_NODES) {
                #pragma unroll
                for (int j = 0; j < 4; j++) {
                    int gcol = n0 + wn + j * 16 + l16;
                    Enc[(size_t)grow * D_OUT + gcol] = f2bf(acc[i][j][r] + bv[j]);
                }
            }
        }
    }
}

// ---------------------------------------------------------------------------
// Kernel 3: out[b,:] = sum_k val[b,k] * Enc[idx[b,k],:]   (f32 out)
// 1 KB rows, bias folded into Enc. ~218us by subtraction; each wave reads a
// full 1KB row coalesced, 8 loads/thread in flight -> throughput-bound on
// the L3/fabric random-row ceiling (~2.5 TB/s). Untouched.
// ---------------------------------------------------------------------------
__global__ __launch_bounds__(256) void gather_out_kernel(
        const ushort_t* __restrict__ Enc, const int* __restrict__ idx,
        const float* __restrict__ val, float* __restrict__ out) {
    int b = blockIdx.x;
    int t = threadIdx.x;

    __shared__ int   sidx[K_NB];
    __shared__ float sval[K_NB];
    __shared__ float part[8 * 3 * 64];   // [e][h-1][c], conflict-free
    if (t < K_NB) {
        sidx[t] = idx[b * K_NB + t];
        sval[t] = val[b * K_NB + t];
    }
    __syncthreads();

    int h = t >> 6;      // neighbor group: rows k = h + 4*j, j = 0..15
    int c = t & 63;      // 16B chunk within the 1KB row

    float acc[8] = {0.f, 0.f, 0.f, 0.f, 0.f, 0.f, 0.f, 0.f};

    uint4 x[8];
    #pragma unroll
    for (int u = 0; u < 8; u++)
        x[u] = ((const uint4*)(Enc + (size_t)sidx[h + 4 * u] * D_OUT))[c];

    #pragma unroll
    for (int j0 = 0; j0 < 16; j0 += 8) {
        uint4 cur[8];
        #pragma unroll
        for (int u = 0; u < 8; u++) cur[u] = x[u];
        if (j0 + 8 < 16) {
            #pragma unroll
            for (int u = 0; u < 8; u++)
                x[u] = ((const uint4*)(
                    Enc + (size_t)sidx[h + 4 * (j0 + 8 + u)] * D_OUT))[c];
        }
        #pragma unroll
        for (int u = 0; u < 8; u++) {
            float v = sval[h + 4 * (j0 + u)];
            acc[0] = fmaf(v, bflo(cur[u].x), acc[0]);
            acc[1] = fmaf(v, bfhi(cur[u].x), acc[1]);
            acc[2] = fmaf(v, bflo(cur[u].y), acc[2]);
            acc[3] = fmaf(v, bfhi(cur[u].y), acc[3]);
            acc[4] = fmaf(v, bflo(cur[u].z), acc[4]);
            acc[5] = fmaf(v, bfhi(cur[u].z), acc[5]);
            acc[6] = fmaf(v, bflo(cur[u].w), acc[6]);
            acc[7] = fmaf(v, bfhi(cur[u].w), acc[7]);
        }
    }

    if (h != 0) {
        #pragma unroll
        for (int e = 0; e < 8; e++)
            part[e * 192 + (h - 1) * 64 + c] = acc[e];
    }
    __syncthreads();
    if (h == 0) {
        float r[8];
        #pragma unroll
        for (int e = 0; e < 8; e++)
            r[e] = acc[e] + part[e * 192 + c] + part[e * 192 + 64 + c]
                          + part[e * 192 + 128 + c];
        float4 o0 = {r[0], r[1], r[2], r[3]};
        float4 o1 = {r[4], r[5], r[6], r[7]};
        float* dst = out + (size_t)b * D_OUT + c * 8;
        *(float4*)(dst)     = o0;
        *(float4*)(dst + 4) = o1;
    }
}

// ---------------------------------------------------------------------------
// Fallback kernels (tiny workspace): gather in X-domain (f32) + small GEMM.
// ---------------------------------------------------------------------------
__global__ __launch_bounds__(256) void gather_f32_kernel(
        const float* __restrict__ X, const int* __restrict__ idx,
        const float* __restrict__ val, ushort_t* __restrict__ Y,
        float* __restrict__ s) {
    int b = blockIdx.x;
    int t = threadIdx.x;

    __shared__ int   sidx[K_NB];
    __shared__ float sval[K_NB];
    if (t < K_NB) {
        sidx[t] = idx[b * K_NB + t];
        sval[t] = val[b * K_NB + t];
    }
    __syncthreads();

    float ax = 0.f, ay = 0.f, az = 0.f, aw = 0.f;
    #pragma unroll 8
    for (int k = 0; k < K_NB; k++) {
        const float4* row = (const float4*)(X + (size_t)sidx[k] * D_IN);
        float4 x = row[t];
        float  v = sval[k];
        ax = fmaf(v, x.x, ax);
        ay = fmaf(v, x.y, ay);
        az = fmaf(v, x.z, az);
        aw = fmaf(v, x.w, aw);
    }
    uint2 o;
    o.x = (unsigned)f2bf(ax) | ((unsigned)f2bf(ay) << 16);
    o.y = (unsigned)f2bf(az) | ((unsigned)f2bf(aw) << 16);
    *(uint2*)(Y + (size_t)b * D_IN + t * 4) = o;

    if (t == 0) {
        float sum = 0.f;
        #pragma unroll
        for (int k = 0; k < K_NB; k++) sum += sval[k];
        s[b] = sum;
    }
}

__global__ __launch_bounds__(256) void gemm_kernel(
        const ushort_t* __restrict__ Y, const ushort_t* __restrict__ Wt,
        const float* __restrict__ s, const float* __restrict__ bias,
        float* __restrict__ out) {
    const int Kdim = D_IN;
    int m0 = blockIdx.x * 128;
    int n0 = blockIdx.y * 128;
    int t = threadIdx.x;
    int lane = t & 63;
    int wave = t >> 6;
    int wm = (wave >> 1) * 64;
    int wn = (wave & 1) * 64;
    int quad = lane >> 4;
    int l16  = lane & 15;

    __shared__ __align__(16) ushort_t As[128 * 32];
    __shared__ __align__(16) ushort_t Bs[128 * 32];

    f32x4 acc[4][4];
    f32x4 zero = {0.f, 0.f, 0.f, 0.f};
    #pragma unroll
    for (int i = 0; i < 4; i++)
        #pragma unroll
        for (int j = 0; j < 4; j++)
            acc[i][j] = zero;

    int rsw = (l16 >> 2) & 3;

    for (int k0 = 0; k0 < Kdim; k0 += 32) {
        #pragma unroll
        for (int i = 0; i < 2; i++) {
            int c   = t + i * 256;
            int row = c >> 2;
            int chk = c & 3;
            int pos = chk ^ ((row >> 2) & 3);
            *(int4*)(As + row * 32 + pos * 8) =
                *(const int4*)(Y + (size_t)(m0 + row) * Kdim + k0 + chk * 8);
            *(int4*)(Bs + row * 32 + pos * 8) =
                *(const int4*)(Wt + (size_t)(n0 + row) * Kdim + k0 + chk * 8);
        }
        __syncthreads();

        bf16x8 a[4], b[4];
        int rchk = quad ^ rsw;
        #pragma unroll
        for (int i = 0; i < 4; i++) {
            a[i] = *(const bf16x8*)(As + (wm + i * 16 + l16) * 32 + rchk * 8);
            b[i] = *(const bf16x8*)(Bs + (wn + i * 16 + l16) * 32 + rchk * 8);
        }
        #pragma unroll
        for (int i = 0; i < 4; i++)
            #pragma unroll
            for (int j = 0; j < 4; j++)
                acc[i][j] = __builtin_amdgcn_mfma_f32_16x16x32_bf16(
                                a[i], b[j], acc[i][j], 0, 0, 0);
        __syncthreads();
    }

    #pragma unroll
    for (int i = 0; i < 4; i++) {
        #pragma unroll
        for (int r = 0; r < 4; r++) {
            int grow = m0 + wm + i * 16 + quad * 4 + r;
            float sv = s[grow];
            #pragma unroll
            for (int j = 0; j < 4; j++) {
                int gcol = n0 + wn + j * 16 + l16;
                out[(size_t)grow * D_OUT + gcol] = acc[i][j][r] + sv * bias[gcol];
            }
        }
    }
}

// ---------------------------------------------------------------------------
extern "C" void kernel_launch(void* const* d_in, const int* in_sizes, int n_in,
                              void* d_out, int out_size, void* d_ws, size_t ws_size,
                              hipStream_t stream) {
    const float* X    = (const float*)d_in[0];
    const int*   idx  = (const int*)d_in[1];
    const float* val  = (const float*)d_in[2];
    const float* W    = (const float*)d_in[3];
    const float* bias = (const float*)d_in[4];
    float* out = (float*)d_out;

    const size_t ENC_BYTES = (size_t)M_PAD * D_OUT * 2;   // padded bf16 Enc
    const size_t WT_BYTES  = (size_t)D_OUT * D_IN * 2;
    const size_t Y_BYTES   = (size_t)B_SZ * D_IN * 2;     // fallback only

    char* ws = (char*)d_ws;
    bool fast = ws_size >= ENC_BYTES + WT_BYTES;

    if (fast) {
        ushort_t* Enc = (ushort_t*)ws;
        ushort_t* Wt  = (ushort_t*)(ws + ENC_BYTES);

        hipLaunchKernelGGL(cast_w_kernel, dim3((D_OUT * D_IN) / 256), dim3(256),
                           0, stream, W, Wt);
        hipLaunchKernelGGL(encode_gemm_kernel, dim3((M_PAD / 128) * (D_OUT / 128)),
                           dim3(256), 0, stream, X, Wt, bias, Enc);
        hipLaunchKernelGGL(gather_out_kernel, dim3(B_SZ), dim3(256),
                           0, stream, Enc, idx, val, out);
    } else {
        ushort_t* Yb = (ushort_t*)ws;
        ushort_t* Wt = (ushort_t*)(ws + Y_BYTES);
        float*    sb = (float*)(ws + Y_BYTES + WT_BYTES);

        hipLaunchKernelGGL(cast_w_kernel, dim3((D_OUT * D_IN) / 256), dim3(256),
                           0, stream, W, Wt);
        hipLaunchKernelGGL(gather_f32_kernel, dim3(B_SZ), dim3(256),
                           0, stream, X, idx, val, Yb, sb);
        hipLaunchKernelGGL(gemm_kernel, dim3(B_SZ / 128, D_OUT / 128), dim3(256),
                           0, stream, Yb, Wt, sb, bias, out);
    }
}